// Round 1
// baseline (741.167 us; speedup 1.0000x reference)
//
#include <hip/hip_runtime.h>
#include <stdint.h>

#define M_DIM 4096
#define K_DIM 4096
#define N_DIM 11008

typedef _Float16 half2v __attribute__((ext_vector_type(2)));
typedef _Float16 half8  __attribute__((ext_vector_type(8)));
typedef float    f32x4  __attribute__((ext_vector_type(4)));

// cvt_pkrtz returns __fp16x2; route through bits (clang _Float16/__fp16 mismatch).
__device__ __forceinline__ unsigned int pkrtz_bits(float a, float b) {
  typedef __fp16 fp16x2 __attribute__((ext_vector_type(2)));
  union { fp16x2 h; unsigned int u; } c;
  c.h = __builtin_amdgcn_cvt_pkrtz(a, b);
  return c.u;
}

// Pack 8 f32 (exactly-fp16-valued) into fp16, Marlin order {0,4,1,5,2,6,3,7}.
__device__ __forceinline__ half8 pack8(float4 lo, float4 hi) {
  union { unsigned int u[4]; half8 v; } r;
  r.u[0] = pkrtz_bits(lo.x, hi.x);
  r.u[1] = pkrtz_bits(lo.y, hi.y);
  r.u[2] = pkrtz_bits(lo.z, hi.z);
  r.u[3] = pkrtz_bits(lo.w, hi.w);
  return r.v;
}

// Pre-pass: X f32 [M][K] -> fp16 [M][K], k-permuted within each octet.
__global__ __launch_bounds__(256) void convert_x(const float* __restrict__ X,
                                                 _Float16* __restrict__ X16) {
  size_t g = (size_t)blockIdx.x * 256 + threadIdx.x;
  const float4* p = (const float4*)(X + g * 8);
  float4 lo = p[0], hi = p[1];
  *(half8*)(X16 + g * 8) = pack8(lo, hi);
}

// 8 nibbles -> 8 fp16 (q - (z+1)), Marlin order; zoff = half2(1025+z,1025+z).
__device__ __forceinline__ half8 unpack8(unsigned int q, half2v zoff) {
  union { unsigned int u; half2v h; } t0, t1, t2, t3;
  t0.u = (q & 0x000F000Fu) | 0x64006400u;
  t1.u = ((q >> 4) & 0x000F000Fu) | 0x64006400u;
  t2.u = ((q >> 8) & 0x000F000Fu) | 0x64006400u;
  t3.u = ((q >> 12) & 0x000F000Fu) | 0x64006400u;
  union { half2v h[4]; half8 v; } r;
  r.h[0] = t0.h - zoff;
  r.h[1] = t1.h - zoff;
  r.h[2] = t2.h - zoff;
  r.h[3] = t3.h - zoff;
  return r.v;
}

// Async global->LDS, 16B/lane. LDS dst = wave-uniform base + lane*16 (m97 pattern).
__device__ __forceinline__ void stage16(const void* g, void* l) {
  __builtin_amdgcn_global_load_lds((__attribute__((address_space(1))) unsigned int*)g,
                                   (__attribute__((address_space(3))) unsigned int*)l,
                                   16, 0, 0);
}

// 256x128 block, BK=64, double-buffered LDS (2x32KB), ONE barrier per stage.
// 4 waves in 2x2 grid, each 128m x 64n = 8x4 MFMA 16x16x32_f16.
// Rationale (r0): kernel was latency-bound (MfmaUtil 33%, true-VALU ~14%,
// HBM 17%). Doubling M-tile doubles MFMA per barrier/per dequant: ~1240
// SIMD-cyc of MFMA per stage covers HBM latency of next-stage staging.
// A: global_load_lds -> LDS [buf][octet:8][m:256] 16B chunks.
// B: register-direct packed int4, prefetched one stage ahead; staging + prefetch
// issue at stage TOP so the barrier's vmcnt(0) drain is hidden behind compute.
__global__ __launch_bounds__(256, 2) void gptq_gemm(
    const _Float16* __restrict__ X16,   // fp16 [M][K], Marlin octet order (d_ws)
    const int* __restrict__ QW,         // int32 [K/8][N]
    const int* __restrict__ QZ,         // int32 [1][N/8]
    const float* __restrict__ SC,       // f32 [1][N]
    float* __restrict__ OUT) {          // f32 [M][N]
  const int tid  = threadIdx.x;
  const int lane = tid & 63;
  const int wave = tid >> 6;
  const int wr   = wave >> 1;
  const int wc   = wave & 1;
  const int quad = lane >> 4;
  const int l16  = lane & 15;
  const int bx = blockIdx.x;   // 86
  const int by = blockIdx.y;   // 16

  __shared__ __align__(16) _Float16 ldsA[2 * 2048 * 8];  // 64 KB

  // Staging: thread t owns row (by*256+t), stages 8 octet-chunks of 16B.
  // LDS chunk index c = i*256 + t  ->  octet = i, m = t; addr = c*16 bytes.
  const _Float16* gA = X16 + (size_t)(by * 256 + tid) * K_DIM;
  _Float16* lA = ldsA + (size_t)tid * 8;

  // B: frag row (stage ks, step s) = ks*8 + s*4 + quad; col = bx*128+wc*64+nt*16+l16.
  const int* qp = QW + (size_t)quad * N_DIM + bx * 128 + wc * 64 + l16;

  half2v zoff[4];
  float sc[4];
#pragma unroll
  for (int nt = 0; nt < 4; ++nt) {
    int n = bx * 128 + wc * 64 + nt * 16 + l16;
    int z = (QZ[n >> 3] >> ((n & 7) * 4)) & 15;
    union { unsigned int u; half2v h; } zc;
    unsigned int zb = 0x6400u + (unsigned int)(z + 1);   // fp16 bits of 1025+z
    zc.u = (zb << 16) | zb;
    zoff[nt] = zc.h;
    sc[nt] = SC[n];
  }

  f32x4 acc[8][4] = {};

  // Prologue: stage 0 -> buf 0; prefetch B stage 0.
#pragma unroll
  for (int i = 0; i < 8; ++i)
    stage16(gA + i * 8, lA + i * 2048);
  int q[2][4];
#pragma unroll
  for (int s = 0; s < 2; ++s)
#pragma unroll
    for (int nt = 0; nt < 4; ++nt)
      q[s][nt] = qp[(s * 4) * N_DIM + nt * 16];
  __syncthreads();   // drains staging: buf 0 ready

  int p = 0;
  for (int ks = 0; ks < 64; ++ks) {
    // Issue next stage's A-staging (into other buffer) + B prefetch FIRST.
    int nq[2][4];
    if (ks < 63) {
      gA += 64;
      qp += 8 * N_DIM;
      _Float16* lb = ldsA + (p ^ 1) * 16384 + (size_t)tid * 8;
#pragma unroll
      for (int i = 0; i < 8; ++i)
        stage16(gA + i * 8, lb + i * 2048);
#pragma unroll
      for (int s = 0; s < 2; ++s)
#pragma unroll
        for (int nt = 0; nt < 4; ++nt)
          nq[s][nt] = qp[(s * 4) * N_DIM + nt * 16];
    }

    // Compute current stage from buf p (2 K=32 steps).
    const _Float16* base = ldsA + p * 16384;
#pragma unroll
    for (int s = 0; s < 2; ++s) {
      half8 a[8];
#pragma unroll
      for (int mt = 0; mt < 8; ++mt)
        a[mt] = *(const half8*)(base + ((s * 4 + quad) * 256 + wr * 128 + mt * 16 + l16) * 8);
      half8 b[4];
#pragma unroll
      for (int nt = 0; nt < 4; ++nt)
        b[nt] = unpack8((unsigned int)q[s][nt], zoff[nt]);
#pragma unroll
      for (int mt = 0; mt < 8; ++mt)
#pragma unroll
        for (int nt = 0; nt < 4; ++nt)
          acc[mt][nt] = __builtin_amdgcn_mfma_f32_16x16x32_f16(a[mt], b[nt], acc[mt][nt], 0, 0, 0);
    }
    __syncthreads();   // single barrier: next buf staged + this buf's reads done
    if (ks < 63) {
#pragma unroll
      for (int s = 0; s < 2; ++s)
#pragma unroll
        for (int nt = 0; nt < 4; ++nt)
          q[s][nt] = nq[s][nt];
    }
    p ^= 1;
  }

  // Epilogue: C/D layout col=lane&15, row=quad*4+reg (m89-verified).
#pragma unroll
  for (int mt = 0; mt < 8; ++mt) {
    int mbase = by * 256 + wr * 128 + mt * 16 + quad * 4;
#pragma unroll
    for (int nt = 0; nt < 4; ++nt) {
      int n = bx * 128 + wc * 64 + nt * 16 + l16;
      float s = sc[nt];
#pragma unroll
      for (int pp = 0; pp < 4; ++pp)
        OUT[(size_t)(mbase + pp) * N_DIM + n] = acc[mt][nt][pp] * s;
    }
  }
}

extern "C" void kernel_launch(void* const* d_in, const int* in_sizes, int n_in,
                              void* d_out, int out_size, void* d_ws, size_t ws_size,
                              hipStream_t stream) {
  const float* X  = (const float*)d_in[0];
  const int* QW   = (const int*)d_in[1];
  const int* QZ   = (const int*)d_in[2];
  const float* SC = (const float*)d_in[3];
  float* OUT      = (float*)d_out;
  _Float16* X16   = (_Float16*)d_ws;   // 32 MiB; PRE path verified on HW in round 7

  convert_x<<<dim3((M_DIM * (size_t)K_DIM / 8) / 256), 256, 0, stream>>>(X, X16);
  dim3 grid(N_DIM / 128, M_DIM / 256);
  gptq_gemm<<<grid, 256, 0, stream>>>(X16, QW, QZ, SC, OUT);
}

// Round 2
// 643.478 us; speedup vs baseline: 1.1518x; 1.1518x over previous
//
#include <hip/hip_runtime.h>
#include <stdint.h>

#define M_DIM 4096
#define K_DIM 4096
#define N_DIM 11008

typedef _Float16 half2v __attribute__((ext_vector_type(2)));
typedef _Float16 half8  __attribute__((ext_vector_type(8)));
typedef float    f32x4  __attribute__((ext_vector_type(4)));

#define SCHED_FENCE() __builtin_amdgcn_sched_barrier(0)

// cvt_pkrtz returns __fp16x2; route through bits (clang _Float16/__fp16 mismatch).
__device__ __forceinline__ unsigned int pkrtz_bits(float a, float b) {
  typedef __fp16 fp16x2 __attribute__((ext_vector_type(2)));
  union { fp16x2 h; unsigned int u; } c;
  c.h = __builtin_amdgcn_cvt_pkrtz(a, b);
  return c.u;
}

// Pack 8 f32 (exactly-fp16-valued) into fp16, Marlin order {0,4,1,5,2,6,3,7}.
__device__ __forceinline__ half8 pack8(float4 lo, float4 hi) {
  union { unsigned int u[4]; half8 v; } r;
  r.u[0] = pkrtz_bits(lo.x, hi.x);
  r.u[1] = pkrtz_bits(lo.y, hi.y);
  r.u[2] = pkrtz_bits(lo.z, hi.z);
  r.u[3] = pkrtz_bits(lo.w, hi.w);
  return r.v;
}

// Pre-pass: X f32 [M][K] -> fp16 [M][K], k-permuted within each octet.
__global__ __launch_bounds__(256) void convert_x(const float* __restrict__ X,
                                                 _Float16* __restrict__ X16) {
  size_t g = (size_t)blockIdx.x * 256 + threadIdx.x;
  const float4* p = (const float4*)(X + g * 8);
  float4 lo = p[0], hi = p[1];
  *(half8*)(X16 + g * 8) = pack8(lo, hi);
}

// 8 nibbles -> 8 fp16 (q - (z+1)), Marlin order; zoff = half2(1025+z,1025+z).
__device__ __forceinline__ half8 unpack8(unsigned int q, half2v zoff) {
  union { unsigned int u; half2v h; } t0, t1, t2, t3;
  t0.u = (q & 0x000F000Fu) | 0x64006400u;
  t1.u = ((q >> 4) & 0x000F000Fu) | 0x64006400u;
  t2.u = ((q >> 8) & 0x000F000Fu) | 0x64006400u;
  t3.u = ((q >> 12) & 0x000F000Fu) | 0x64006400u;
  union { half2v h[4]; half8 v; } r;
  r.h[0] = t0.h - zoff;
  r.h[1] = t1.h - zoff;
  r.h[2] = t2.h - zoff;
  r.h[3] = t3.h - zoff;
  return r.v;
}

// Async global->LDS, 16B/lane. LDS dst = wave-uniform base + lane*16 (m97 pattern).
__device__ __forceinline__ void stage16(const void* g, void* l) {
  __builtin_amdgcn_global_load_lds((__attribute__((address_space(1))) unsigned int*)g,
                                   (__attribute__((address_space(3))) unsigned int*)l,
                                   16, 0, 0);
}

// 128x128 block, BK=64, TRIPLE-buffered LDS (3x16KB), 2-stage-ahead prefetch,
// counted vmcnt (T3+T4): each stage issues exactly 12 VMEM events (4 A gload_lds
// + 8 B dword loads) for stage ks+2; end-of-stage barrier waits vmcnt(12) --
// drains the PREVIOUS stage's 12 (A-buffer needed next stage), leaves this
// stage's 12 in flight across the barrier. No vmcnt(0) drain in main loop.
// r1 rationale: r0's 256-tile cut occupancy 3->2 blocks/CU and regressed
// (m132 failure mode); the real cost is the per-stage vmcnt(0) drain.
__global__ __launch_bounds__(256, 3) void gptq_gemm(
    const _Float16* __restrict__ X16,   // fp16 [M][K], Marlin octet order (d_ws)
    const int* __restrict__ QW,         // int32 [K/8][N]
    const int* __restrict__ QZ,         // int32 [1][N/8]
    const float* __restrict__ SC,       // f32 [1][N]
    float* __restrict__ OUT) {          // f32 [M][N]
  const int tid  = threadIdx.x;
  const int lane = tid & 63;
  const int wave = tid >> 6;
  const int wr   = wave >> 1;
  const int wc   = wave & 1;
  const int quad = lane >> 4;
  const int l16  = lane & 15;
  const int bx = blockIdx.x;   // 86
  const int by = blockIdx.y;   // 32

  __shared__ __align__(16) _Float16 ldsA[3 * 1024 * 8];  // 48 KB, 3 buffers

  // Staging: thread t stages chunks c_i = i*256+t (i=0..3); octet=c>>7, m=c&127.
  const _Float16* gA = X16 + (size_t)(by * 128 + (tid & 127)) * K_DIM + (tid >> 7) * 8;
  _Float16* lw = ldsA + (size_t)tid * 8;

  // B: frag row (stage ks, step s) = ks*8 + s*4 + quad; col = bx*128+wc*64+nt*16+l16.
  const int* qp = QW + (size_t)quad * N_DIM + bx * 128 + wc * 64 + l16;

  half2v zoff[4];
  float sc[4];
#pragma unroll
  for (int nt = 0; nt < 4; ++nt) {
    int n = bx * 128 + wc * 64 + nt * 16 + l16;
    int z = (QZ[n >> 3] >> ((n & 7) * 4)) & 15;
    union { unsigned int u; half2v h; } zc;
    unsigned int zb = 0x6400u + (unsigned int)(z + 1);   // fp16 bits of 1025+z
    zc.u = (zb << 16) | zb;
    zoff[nt] = zc.h;
    sc[nt] = SC[n];
  }

  f32x4 acc[4][4] = {};

  // ---- Prologue: stage 0 -> buf0, stage 1 -> buf1; B q0 (stage 0), q1 (stage 1).
  int q0[2][4], q1[2][4];
#pragma unroll
  for (int i = 0; i < 4; ++i)
    stage16(gA + i * 16, lw + i * 2048);
  SCHED_FENCE();
#pragma unroll
  for (int s = 0; s < 2; ++s)
#pragma unroll
    for (int nt = 0; nt < 4; ++nt)
      q0[s][nt] = qp[(s * 4) * N_DIM + nt * 16];
  SCHED_FENCE();
  gA += 64;
  qp += 8 * N_DIM;
#pragma unroll
  for (int i = 0; i < 4; ++i)
    stage16(gA + i * 16, lw + 8192 + i * 2048);
  SCHED_FENCE();
#pragma unroll
  for (int s = 0; s < 2; ++s)
#pragma unroll
    for (int nt = 0; nt < 4; ++nt)
      q1[s][nt] = qp[(s * 4) * N_DIM + nt * 16];
  SCHED_FENCE();
  // Drain stage-0's 12 (A0 ready, q0 ready); leave stage-1's 12 in flight.
  asm volatile("s_waitcnt vmcnt(12)" ::: "memory");
  __builtin_amdgcn_s_barrier();

  int rb = 0;  // buffer read this stage (= ks % 3)
  int wb = 2;  // buffer written this stage (= (ks+2) % 3)
  for (int ks = 0; ks < 64; ++ks) {
    // Issue stage ks+2's A-staging + B prefetch FIRST (12 VMEM events).
    int nq[2][4];
    if (ks < 62) {
      gA += 64;
      qp += 8 * N_DIM;
      _Float16* lb = ldsA + wb * 8192 + (size_t)tid * 8;
#pragma unroll
      for (int i = 0; i < 4; ++i)
        stage16(gA + i * 16, lb + i * 2048);
#pragma unroll
      for (int s = 0; s < 2; ++s)
#pragma unroll
        for (int nt = 0; nt < 4; ++nt)
          nq[s][nt] = qp[(s * 4) * N_DIM + nt * 16];
      SCHED_FENCE();   // pin: all 12 issued before compute & before the vmcnt
    }

    // Compute current stage from buf rb (2 K=32 steps), B from q0.
    const _Float16* base = ldsA + rb * 8192;
#pragma unroll
    for (int s = 0; s < 2; ++s) {
      half8 a[4];
#pragma unroll
      for (int mt = 0; mt < 4; ++mt)
        a[mt] = *(const half8*)(base + ((s * 4 + quad) * 128 + wr * 64 + mt * 16 + l16) * 8);
      half8 b[4];
#pragma unroll
      for (int nt = 0; nt < 4; ++nt)
        b[nt] = unpack8((unsigned int)q0[s][nt], zoff[nt]);
      __builtin_amdgcn_s_setprio(1);
#pragma unroll
      for (int mt = 0; mt < 4; ++mt)
#pragma unroll
        for (int nt = 0; nt < 4; ++nt)
          acc[mt][nt] = __builtin_amdgcn_mfma_f32_16x16x32_f16(a[mt], b[nt], acc[mt][nt], 0, 0, 0);
      __builtin_amdgcn_s_setprio(0);
    }

    // Rotate B prefetch registers and buffer indices.
#pragma unroll
    for (int s = 0; s < 2; ++s)
#pragma unroll
      for (int nt = 0; nt < 4; ++nt) {
        q0[s][nt] = q1[s][nt];
        if (ks < 62) q1[s][nt] = nq[s][nt];
      }
    rb = (rb == 2) ? 0 : rb + 1;
    wb = (wb == 2) ? 0 : wb + 1;

    // Barrier with COUNTED vmcnt: drain previous stage's 12 (next buf ready),
    // keep this stage's 12 in flight. Full drain only at the tail.
    if (ks < 63) {
      SCHED_FENCE();
      if (ks < 62)
        asm volatile("s_waitcnt vmcnt(12)" ::: "memory");
      else
        asm volatile("s_waitcnt vmcnt(0)" ::: "memory");
      __builtin_amdgcn_s_barrier();
    }
  }

  // Epilogue: C/D layout col=lane&15, row=quad*4+reg (m89-verified).
#pragma unroll
  for (int mt = 0; mt < 4; ++mt) {
    int mbase = by * 128 + wr * 64 + mt * 16 + quad * 4;
#pragma unroll
    for (int nt = 0; nt < 4; ++nt) {
      int n = bx * 128 + wc * 64 + nt * 16 + l16;
      float s = sc[nt];
#pragma unroll
      for (int pp = 0; pp < 4; ++pp)
        OUT[(size_t)(mbase + pp) * N_DIM + n] = acc[mt][nt][pp] * s;
    }
  }
}

extern "C" void kernel_launch(void* const* d_in, const int* in_sizes, int n_in,
                              void* d_out, int out_size, void* d_ws, size_t ws_size,
                              hipStream_t stream) {
  const float* X  = (const float*)d_in[0];
  const int* QW   = (const int*)d_in[1];
  const int* QZ   = (const int*)d_in[2];
  const float* SC = (const float*)d_in[3];
  float* OUT      = (float*)d_out;
  _Float16* X16   = (_Float16*)d_ws;   // 32 MiB; PRE path verified on HW in round 7

  convert_x<<<dim3((M_DIM * (size_t)K_DIM / 8) / 256), 256, 0, stream>>>(X, X16);
  dim3 grid(N_DIM / 128, M_DIM / 128);
  gptq_gemm<<<grid, 256, 0, stream>>>(X16, QW, QZ, SC, OUT);
}